// Round 1
// baseline (149.337 us; speedup 1.0000x reference)
//
#include <hip/hip_runtime.h>
#include <hip/hip_bf16.h>

// Problem constants (fixed shape: B=4096, I=1024, H=1024)
#define B_ROWS 4096
#define H_DIM  1024
#define K_DIM  2048   // I + H
#define N_DIM  4096   // 4H

typedef __attribute__((ext_vector_type(8))) short bf16x8;
typedef __attribute__((ext_vector_type(4))) float f32x4;

__device__ __forceinline__ unsigned short f2bf(float f) {
  union { float f; unsigned int u; } v; v.f = f;
  unsigned int u = v.u;
  unsigned int r = (u + 0x7fffu + ((u >> 16) & 1u)) >> 16;
  return (unsigned short)r;
}

__device__ __forceinline__ void gload_lds16(const void* g, void* l) {
  __builtin_amdgcn_global_load_lds(
      (const __attribute__((address_space(1))) void*)g,
      (__attribute__((address_space(3))) void*)l, 16, 0, 0);
}

// -------- pack kernels: fp32 -> bf16 ---------------------------------------
// A = concat(x, h) row-major [4096][2048] bf16
__global__ __launch_bounds__(256) void pack_a_kernel(
    const float* __restrict__ x, const float* __restrict__ h,
    unsigned short* __restrict__ out) {
  int t = blockIdx.x * 256 + threadIdx.x;
  int e = t * 4;                       // element index, groups never straddle 1024
  int row = e >> 11;
  int col = e & 2047;
  const float* src = (col < 1024) ? (x + (size_t)row * 1024 + col)
                                  : (h + (size_t)row * 1024 + (col - 1024));
  float4 v = *(const float4*)src;
  ushort4 o;
  o.x = f2bf(v.x); o.y = f2bf(v.y); o.z = f2bf(v.z); o.w = f2bf(v.w);
  *(ushort4*)(out + e) = o;
}

__global__ __launch_bounds__(256) void pack_w_kernel(
    const float* __restrict__ W, unsigned short* __restrict__ out) {
  int t = blockIdx.x * 256 + threadIdx.x;
  int e = t * 4;
  float4 v = *(const float4*)(W + e);
  ushort4 o;
  o.x = f2bf(v.x); o.y = f2bf(v.y); o.z = f2bf(v.z); o.w = f2bf(v.w);
  *(ushort4*)(out + e) = o;
}

// -------- GEMM: gates = A (MxK) * W^T (NxK), fp32 out ----------------------
// m97 structure: 128x128 tile, BK=32, 4 waves (2x2), each wave 64x64 = 4x4
// frags of 16x16x32 MFMA; global_load_lds width-16 staging; 2-barrier K-loop.
__global__ __launch_bounds__(256) void gemm_kernel(
    const unsigned short* __restrict__ A, const unsigned short* __restrict__ W,
    float* __restrict__ C) {
  __shared__ __align__(16) unsigned short As[128 * 32];
  __shared__ __align__(16) unsigned short Bs[128 * 32];

  const int tid = threadIdx.x;
  const int w = tid >> 6, l = tid & 63;
  const int wm = w >> 1, wn = w & 1;       // wave grid 2x2 -> 64x64 each
  const int lm = l & 15, kq = l >> 4;      // fragment row/col, k-quarter
  const int bm = blockIdx.y * 128, bn = blockIdx.x * 128;

  const int srow = w * 16 + (l >> 2);      // staging row within tile (round 0)
  const int kg = l & 3;                    // 8-elem (16B) group within BK=32

  f32x4 acc[4][4];
#pragma unroll
  for (int i = 0; i < 4; i++)
#pragma unroll
    for (int j = 0; j < 4; j++) acc[i][j] = (f32x4)0.0f;

  for (int k0 = 0; k0 < K_DIM; k0 += 32) {
    // stage A and B tiles (each 128 rows x 32 cols bf16 = 8 KB)
#pragma unroll
    for (int r = 0; r < 2; r++) {
      int rit = r * 64 + srow;
      gload_lds16(A + (size_t)(bm + rit) * K_DIM + k0 + kg * 8,
                  &As[(r * 64 + w * 16) * 32]);
      gload_lds16(W + (size_t)(bn + rit) * K_DIM + k0 + kg * 8,
                  &Bs[(r * 64 + w * 16) * 32]);
    }
    __syncthreads();

    bf16x8 av[4], bv[4];
#pragma unroll
    for (int mi = 0; mi < 4; mi++)
      av[mi] = *(const bf16x8*)&As[(wm * 64 + mi * 16 + lm) * 32 + kq * 8];
#pragma unroll
    for (int ni = 0; ni < 4; ni++)
      bv[ni] = *(const bf16x8*)&Bs[(wn * 64 + ni * 16 + lm) * 32 + kq * 8];
#pragma unroll
    for (int mi = 0; mi < 4; mi++)
#pragma unroll
      for (int ni = 0; ni < 4; ni++)
        acc[mi][ni] = __builtin_amdgcn_mfma_f32_16x16x32_bf16(
            av[mi], bv[ni], acc[mi][ni], 0, 0, 0);
    __syncthreads();
  }

  // epilogue: C/D layout col = lane&15, row = (lane>>4)*4 + reg
  float* Cb = C + (size_t)(bm + wm * 64) * N_DIM + bn + wn * 64;
#pragma unroll
  for (int mi = 0; mi < 4; mi++)
#pragma unroll
    for (int ni = 0; ni < 4; ni++)
#pragma unroll
      for (int j = 0; j < 4; j++)
        Cb[(size_t)(mi * 16 + kq * 4 + j) * N_DIM + ni * 16 + lm] =
            acc[mi][ni][j];
}

// -------- fused LN + activations + cell update -----------------------------
__device__ __forceinline__ float2 blk_sum2(float s, float q, float* red,
                                           int wid, int lane) {
#pragma unroll
  for (int o = 32; o >= 1; o >>= 1) {
    s += __shfl_xor(s, o, 64);
    q += __shfl_xor(q, o, 64);
  }
  __syncthreads();  // protect red from previous use
  if (lane == 0) { red[wid * 2] = s; red[wid * 2 + 1] = q; }
  __syncthreads();
  s = red[0] + red[2] + red[4] + red[6];
  q = red[1] + red[3] + red[5] + red[7];
  return make_float2(s, q);
}

__device__ __forceinline__ float sigmoidf_(float x) {
  return 1.0f / (1.0f + __expf(-x));
}
__device__ __forceinline__ float tanhf_(float x) {
  return 1.0f - 2.0f / (__expf(2.0f * x) + 1.0f);
}

__global__ __launch_bounds__(256) void ln_lstm_kernel(
    const float* __restrict__ gates, const float* __restrict__ cprev,
    const float* __restrict__ bias,
    const float* __restrict__ g_i, const float* __restrict__ b_i,
    const float* __restrict__ g_f, const float* __restrict__ b_f,
    const float* __restrict__ g_g, const float* __restrict__ b_g,
    const float* __restrict__ g_o, const float* __restrict__ b_o,
    const float* __restrict__ g_c, const float* __restrict__ b_c,
    float* __restrict__ out) {
  const int b = blockIdx.x;
  const int t = threadIdx.x;
  const int wid = t >> 6, lane = t & 63;
  __shared__ float red[8];

  const float* grow = gates + (size_t)b * N_DIM;
  const int c0 = t * 4;  // 4 consecutive columns per thread

  // load 4 gates + bias
  float4 v[4];
#pragma unroll
  for (int g = 0; g < 4; g++) {
    float4 raw = *(const float4*)(grow + g * 1024 + c0);
    float4 bb = *(const float4*)(bias + g * 1024 + c0);
    raw.x += bb.x; raw.y += bb.y; raw.z += bb.z; raw.w += bb.w;
    v[g] = raw;
  }

  const float4 gamma[4] = {*(const float4*)(g_i + c0), *(const float4*)(g_f + c0),
                           *(const float4*)(g_g + c0), *(const float4*)(g_o + c0)};
  const float4 beta[4]  = {*(const float4*)(b_i + c0), *(const float4*)(b_f + c0),
                           *(const float4*)(b_g + c0), *(const float4*)(b_o + c0)};

  float a[4][4];  // activated gate values [gate][elem]
#pragma unroll
  for (int g = 0; g < 4; g++) {
    float* e = (float*)&v[g];
    float s = e[0] + e[1] + e[2] + e[3];
    float q = e[0]*e[0] + e[1]*e[1] + e[2]*e[2] + e[3]*e[3];
    float2 r = blk_sum2(s, q, red, wid, lane);
    float mu = r.x * (1.0f / 1024.0f);
    float var = r.y * (1.0f / 1024.0f) - mu * mu;
    float inv = rsqrtf(var + 1e-5f);
    const float* gm = (const float*)&gamma[g];
    const float* bt = (const float*)&beta[g];
#pragma unroll
    for (int j = 0; j < 4; j++) {
      float n = (e[j] - mu) * inv * gm[j] + bt[j];
      a[g][j] = (g == 2) ? tanhf_(n) : sigmoidf_(n);
    }
  }

  // cell update
  float4 cp = *(const float4*)(cprev + (size_t)b * 1024 + c0);
  float cn[4];
  const float* cpe = (const float*)&cp;
#pragma unroll
  for (int j = 0; j < 4; j++)
    cn[j] = a[1][j] * cpe[j] + a[0][j] * a[2][j];

  // LN over c_new, then h = o * tanh(LN(c_new))
  {
    float s = cn[0] + cn[1] + cn[2] + cn[3];
    float q = cn[0]*cn[0] + cn[1]*cn[1] + cn[2]*cn[2] + cn[3]*cn[3];
    float2 r = blk_sum2(s, q, red, wid, lane);
    float mu = r.x * (1.0f / 1024.0f);
    float var = r.y * (1.0f / 1024.0f) - mu * mu;
    float inv = rsqrtf(var + 1e-5f);
    float4 gm = *(const float4*)(g_c + c0);
    float4 bt = *(const float4*)(b_c + c0);
    const float* gme = (const float*)&gm;
    const float* bte = (const float*)&bt;
    float hn[4];
#pragma unroll
    for (int j = 0; j < 4; j++) {
      float n = (cn[j] - mu) * inv * gme[j] + bte[j];
      hn[j] = a[3][j] * tanhf_(n);
    }
    *(float4*)(out + (size_t)b * 1024 + c0) = make_float4(hn[0], hn[1], hn[2], hn[3]);
    *(float4*)(out + (size_t)B_ROWS * H_DIM + (size_t)b * 1024 + c0) =
        make_float4(cn[0], cn[1], cn[2], cn[3]);
  }
}

// ---------------------------------------------------------------------------
extern "C" void kernel_launch(void* const* d_in, const int* in_sizes, int n_in,
                              void* d_out, int out_size, void* d_ws,
                              size_t ws_size, hipStream_t stream) {
  const float* x    = (const float*)d_in[0];
  const float* h    = (const float*)d_in[1];
  const float* c    = (const float*)d_in[2];
  const float* W    = (const float*)d_in[3];
  const float* bias = (const float*)d_in[4];
  const float* ln_i_g = (const float*)d_in[5];
  const float* ln_i_b = (const float*)d_in[6];
  const float* ln_f_g = (const float*)d_in[7];
  const float* ln_f_b = (const float*)d_in[8];
  const float* ln_g_g = (const float*)d_in[9];
  const float* ln_g_b = (const float*)d_in[10];
  const float* ln_o_g = (const float*)d_in[11];
  const float* ln_o_b = (const float*)d_in[12];
  const float* ln_c_g = (const float*)d_in[13];
  const float* ln_c_b = (const float*)d_in[14];

  // workspace layout: A_bf16 (16MB) | W_bf16 (16MB) | gates fp32 (64MB)
  unsigned short* Abf = (unsigned short*)d_ws;
  unsigned short* Wbf = Abf + (size_t)B_ROWS * K_DIM;
  float* gates = (float*)(Wbf + (size_t)N_DIM * K_DIM);

  pack_a_kernel<<<(B_ROWS * K_DIM) / (4 * 256), 256, 0, stream>>>(x, h, Abf);
  pack_w_kernel<<<(N_DIM * K_DIM) / (4 * 256), 256, 0, stream>>>(W, Wbf);

  dim3 ggrid(N_DIM / 128, B_ROWS / 128);
  gemm_kernel<<<ggrid, 256, 0, stream>>>(Abf, Wbf, gates);

  ln_lstm_kernel<<<B_ROWS, 256, 0, stream>>>(
      gates, c, bias, ln_i_g, ln_i_b, ln_f_g, ln_f_b, ln_g_g, ln_g_b,
      ln_o_g, ln_o_b, ln_c_g, ln_c_b, (float*)d_out);
}

// Round 2
// 104.573 us; speedup vs baseline: 1.4281x; 1.4281x over previous
//
#include <hip/hip_runtime.h>
#include <hip/hip_bf16.h>

// Fixed shape: B=4096, I=1024, H=1024
#define B_ROWS 4096
#define H_DIM  1024
#define K_DIM  2048   // I + H
#define N_DIM  4096   // 4H
#define NT     32     // K_DIM / 64 K-tiles

typedef __attribute__((ext_vector_type(8))) short bf16x8;
typedef __attribute__((ext_vector_type(4))) float f32x4;

__device__ __forceinline__ unsigned short f2bf(float f) {
  union { float f; unsigned int u; } v; v.f = f;
  unsigned int u = v.u;
  return (unsigned short)((u + 0x7fffu + ((u >> 16) & 1u)) >> 16);
}
__device__ __forceinline__ float bf2f(unsigned short u) {
  union { unsigned int u; float f; } v; v.u = ((unsigned int)u) << 16;
  return v.f;
}

__device__ __forceinline__ void gload_lds16(const void* g, void* l) {
  __builtin_amdgcn_global_load_lds(
      (const __attribute__((address_space(1))) void*)g,
      (__attribute__((address_space(3))) void*)l, 16, 0, 0);
}

// -------- pack kernels: fp32 -> bf16 ---------------------------------------
__global__ __launch_bounds__(256) void pack_a_kernel(
    const float* __restrict__ x, const float* __restrict__ h,
    unsigned short* __restrict__ out) {
  int t = blockIdx.x * 256 + threadIdx.x;
  int e = t * 4;
  int row = e >> 11;
  int col = e & 2047;
  const float* src = (col < 1024) ? (x + (size_t)row * 1024 + col)
                                  : (h + (size_t)row * 1024 + (col - 1024));
  float4 v = *(const float4*)src;
  ushort4 o;
  o.x = f2bf(v.x); o.y = f2bf(v.y); o.z = f2bf(v.z); o.w = f2bf(v.w);
  *(ushort4*)(out + e) = o;
}

__global__ __launch_bounds__(256) void pack_w_kernel(
    const float* __restrict__ W, unsigned short* __restrict__ out) {
  int t = blockIdx.x * 256 + threadIdx.x;
  int e = t * 4;
  float4 v = *(const float4*)(W + e);
  ushort4 o;
  o.x = f2bf(v.x); o.y = f2bf(v.y); o.z = f2bf(v.z); o.w = f2bf(v.w);
  *(ushort4*)(out + e) = o;
}

// -------- GEMM: 256x256 tile, BK=64, 8-phase schedule (m201 template) ------
// gates(bf16) = A(4096x2048 bf16) * W^T(4096x2048 bf16) + bias(fp32)
// 8 waves = 2(M) x 4(N); per-wave 128x64 output; LDS 128KB 2-dbuf,
// st_16x32 swizzle via pre-swizzled global source + swizzled ds_read.

#define STAGE(g, kt, dst) do {                              \
    gload_lds16((g) + (size_t)(kt) * 64, (dst));            \
    gload_lds16((g) + (size_t)(kt) * 64 + 32, (dst) + 1024); } while (0)

#define WAIT_LGKM0() do {                                   \
    asm volatile("s_waitcnt lgkmcnt(0)" ::: "memory");      \
    __builtin_amdgcn_sched_barrier(0); } while (0)

__global__ __launch_bounds__(512, 2) void gemm_kernel(
    const unsigned short* __restrict__ A, const unsigned short* __restrict__ W,
    const float* __restrict__ bias, unsigned short* __restrict__ C) {
  __shared__ __align__(16) char lds[131072];

  const int tid = threadIdx.x;
  const int w = tid >> 6, l = tid & 63;
  const int wm = w >> 2, wn = w & 3;            // 2 x 4 wave grid
  const int bm = blockIdx.y * 256, bn = blockIdx.x * 256;

  // swizzled ds_read lane offset within a 1KB subtile (16 rows x 32 bf16)
  const int lofs = (((l & 15) * 64) + ((l >> 4) * 16)) ^ ((l & 8) << 2);
  // inverse-swizzle lane mapping for linear global_load_lds staging
  const int lane_r = (l >> 2) & 15;
  const int lane_c = ((l & 3) * 8) ^ (((l >> 5) & 1) * 16);

  // per-wave staged row-blocks (16-row units) for each chunk
  const int rbA0 = w + (w & 4);                 // {0..3, 8..11}  (read at P1)
  const int rbA1 = rbA0 + 4;                    // {4..7,12..15}  (read at P3)
  const int rbB0 = ((w >> 1) << 2) + (w & 1);   // {0,1,4,5,...}  (read at P1)
  const int rbB1 = rbB0 + 2;                    //                (read at P2)

  const unsigned short* gA0 = A + (size_t)(bm + rbA0 * 16 + lane_r) * K_DIM + lane_c;
  const unsigned short* gA1 = A + (size_t)(bm + rbA1 * 16 + lane_r) * K_DIM + lane_c;
  const unsigned short* gB0 = W + (size_t)(bn + rbB0 * 16 + lane_r) * K_DIM + lane_c;
  const unsigned short* gB1 = W + (size_t)(bn + rbB1 * 16 + lane_r) * K_DIM + lane_c;

  char* const L0 = lds;
  char* const L1 = lds + 65536;

  f32x4 acc[8][4];
#pragma unroll
  for (int i = 0; i < 8; ++i)
#pragma unroll
    for (int j = 0; j < 4; ++j) acc[i][j] = (f32x4)0.0f;

  // ---- prologue: tile0 fully (4 chunks), tile1 first 3 chunks ----
  STAGE(gA0, 0, L0 + rbA0 * 2048);
  STAGE(gB0, 0, L0 + 32768 + rbB0 * 2048);
  STAGE(gB1, 0, L0 + 32768 + rbB1 * 2048);
  STAGE(gA1, 0, L0 + rbA1 * 2048);
  STAGE(gA0, 1, L1 + rbA0 * 2048);
  STAGE(gB0, 1, L1 + 32768 + rbB0 * 2048);
  STAGE(gB1, 1, L1 + 32768 + rbB1 * 2048);
  asm volatile("s_waitcnt vmcnt(6)" ::: "memory");
  __builtin_amdgcn_s_barrier();

  bf16x8 a[4][2], b0[2][2], b1[2][2];

#pragma unroll 2
  for (int t = 0; t < NT; ++t) {
    const int buf = t & 1;
    char* const Lc = lds + buf * 65536;
    char* const Ln = lds + (buf ^ 1) * 65536;
    const char* const LA = Lc;
    const char* const LB = Lc + 32768;
    const int kt1 = (t + 1) & (NT - 1);   // wrapped: tail prefetch is garbage, never read
    const int kt2 = (t + 2) & (NT - 1);

    // ---------------- P1: read A-half0 + B-half0; stage A1(t+1) ----------
#pragma unroll
    for (int mi = 0; mi < 4; ++mi)
#pragma unroll
      for (int kk = 0; kk < 2; ++kk)
        a[mi][kk] = *(const bf16x8*)(LA + (((wm * 8 + mi) * 2 + kk) << 10) + lofs);
#pragma unroll
    for (int ni = 0; ni < 2; ++ni)
#pragma unroll
      for (int kk = 0; kk < 2; ++kk)
        b0[ni][kk] = *(const bf16x8*)(LB + (((wn * 4 + ni) * 2 + kk) << 10) + lofs);
    STAGE(gA1, kt1, Ln + rbA1 * 2048);
    asm volatile("s_waitcnt lgkmcnt(8)" ::: "memory");
    __builtin_amdgcn_s_barrier();
    WAIT_LGKM0();
    __builtin_amdgcn_s_setprio(1);
#pragma unroll
    for (int mi = 0; mi < 4; ++mi)
#pragma unroll
      for (int ni = 0; ni < 2; ++ni)
#pragma unroll
        for (int kk = 0; kk < 2; ++kk)
          acc[mi][ni] = __builtin_amdgcn_mfma_f32_16x16x32_bf16(
              a[mi][kk], b0[ni][kk], acc[mi][ni], 0, 0, 0);
    __builtin_amdgcn_s_setprio(0);
    __builtin_amdgcn_s_barrier();

    // ---------------- P2: read B-half1; stage A0(t+2) ---------------------
#pragma unroll
    for (int ni = 0; ni < 2; ++ni)
#pragma unroll
      for (int kk = 0; kk < 2; ++kk)
        b1[ni][kk] = *(const bf16x8*)(LB + (((wn * 4 + 2 + ni) * 2 + kk) << 10) + lofs);
    STAGE(gA0, kt2, Lc + rbA0 * 2048);
    __builtin_amdgcn_s_barrier();
    WAIT_LGKM0();
    __builtin_amdgcn_s_setprio(1);
#pragma unroll
    for (int mi = 0; mi < 4; ++mi)
#pragma unroll
      for (int ni = 0; ni < 2; ++ni)
#pragma unroll
        for (int kk = 0; kk < 2; ++kk)
          acc[mi][2 + ni] = __builtin_amdgcn_mfma_f32_16x16x32_bf16(
              a[mi][kk], b1[ni][kk], acc[mi][2 + ni], 0, 0, 0);
    __builtin_amdgcn_s_setprio(0);
    __builtin_amdgcn_s_barrier();

    // ---------------- P3: read A-half1; stage B0(t+2) ---------------------
#pragma unroll
    for (int mi = 0; mi < 4; ++mi)
#pragma unroll
      for (int kk = 0; kk < 2; ++kk)
        a[mi][kk] = *(const bf16x8*)(LA + (((wm * 8 + 4 + mi) * 2 + kk) << 10) + lofs);
    STAGE(gB0, kt2, Lc + 32768 + rbB0 * 2048);
    __builtin_amdgcn_s_barrier();
    WAIT_LGKM0();
    __builtin_amdgcn_s_setprio(1);
#pragma unroll
    for (int mi = 0; mi < 4; ++mi)
#pragma unroll
      for (int ni = 0; ni < 2; ++ni)
#pragma unroll
        for (int kk = 0; kk < 2; ++kk)
          acc[4 + mi][2 + ni] = __builtin_amdgcn_mfma_f32_16x16x32_bf16(
              a[mi][kk], b1[ni][kk], acc[4 + mi][2 + ni], 0, 0, 0);
    __builtin_amdgcn_s_setprio(0);
    __builtin_amdgcn_s_barrier();

    // ---------------- P4: stage B1(t+2); vmcnt(6) -------------------------
    STAGE(gB1, kt2, Lc + 32768 + rbB1 * 2048);
    asm volatile("s_waitcnt vmcnt(6)" ::: "memory");
    __builtin_amdgcn_s_barrier();
    __builtin_amdgcn_s_setprio(1);
#pragma unroll
    for (int mi = 0; mi < 4; ++mi)
#pragma unroll
      for (int ni = 0; ni < 2; ++ni)
#pragma unroll
        for (int kk = 0; kk < 2; ++kk)
          acc[4 + mi][ni] = __builtin_amdgcn_mfma_f32_16x16x32_bf16(
              a[mi][kk], b0[ni][kk], acc[4 + mi][ni], 0, 0, 0);
    __builtin_amdgcn_s_setprio(0);
    __builtin_amdgcn_s_barrier();
  }

  // ---- epilogue: +bias (fp32), convert to bf16, store ----
  const int lm = l & 15, lq = l >> 4;
  float bv[4];
#pragma unroll
  for (int ni = 0; ni < 4; ++ni) bv[ni] = bias[bn + wn * 64 + ni * 16 + lm];
  unsigned short* Cb = C + (size_t)(bm + wm * 128) * N_DIM + bn + wn * 64;
#pragma unroll
  for (int mi = 0; mi < 8; ++mi)
#pragma unroll
    for (int j = 0; j < 4; ++j) {
      const size_t rofs = (size_t)(mi * 16 + lq * 4 + j) * N_DIM;
#pragma unroll
      for (int ni = 0; ni < 4; ++ni)
        Cb[rofs + ni * 16 + lm] = f2bf(acc[mi][ni][j] + bv[ni]);
    }
}

// -------- fused LN + activations + cell update -----------------------------
__device__ __forceinline__ float2 blk_sum2(float s, float q, float* red,
                                           int wid, int lane) {
#pragma unroll
  for (int o = 32; o >= 1; o >>= 1) {
    s += __shfl_xor(s, o, 64);
    q += __shfl_xor(q, o, 64);
  }
  __syncthreads();
  if (lane == 0) { red[wid * 2] = s; red[wid * 2 + 1] = q; }
  __syncthreads();
  s = red[0] + red[2] + red[4] + red[6];
  q = red[1] + red[3] + red[5] + red[7];
  return make_float2(s, q);
}

__device__ __forceinline__ float sigmoidf_(float x) {
  return 1.0f / (1.0f + __expf(-x));
}
__device__ __forceinline__ float tanhf_(float x) {
  return 1.0f - 2.0f / (__expf(2.0f * x) + 1.0f);
}

__global__ __launch_bounds__(256) void ln_lstm_kernel(
    const unsigned short* __restrict__ gates, const float* __restrict__ cprev,
    const float* __restrict__ g_i, const float* __restrict__ b_i,
    const float* __restrict__ g_f, const float* __restrict__ b_f,
    const float* __restrict__ g_g, const float* __restrict__ b_g,
    const float* __restrict__ g_o, const float* __restrict__ b_o,
    const float* __restrict__ g_c, const float* __restrict__ b_c,
    float* __restrict__ out) {
  const int b = blockIdx.x;
  const int t = threadIdx.x;
  const int wid = t >> 6, lane = t & 63;
  __shared__ float red[8];

  const unsigned short* grow = gates + (size_t)b * N_DIM;
  const int c0 = t * 4;

  float v[4][4];
#pragma unroll
  for (int g = 0; g < 4; g++) {
    ushort4 raw = *(const ushort4*)(grow + g * 1024 + c0);
    v[g][0] = bf2f(raw.x); v[g][1] = bf2f(raw.y);
    v[g][2] = bf2f(raw.z); v[g][3] = bf2f(raw.w);
  }

  const float4 gamma[4] = {*(const float4*)(g_i + c0), *(const float4*)(g_f + c0),
                           *(const float4*)(g_g + c0), *(const float4*)(g_o + c0)};
  const float4 beta[4]  = {*(const float4*)(b_i + c0), *(const float4*)(b_f + c0),
                           *(const float4*)(b_g + c0), *(const float4*)(b_o + c0)};

  float a[4][4];
#pragma unroll
  for (int g = 0; g < 4; g++) {
    float s = v[g][0] + v[g][1] + v[g][2] + v[g][3];
    float q = v[g][0]*v[g][0] + v[g][1]*v[g][1] + v[g][2]*v[g][2] + v[g][3]*v[g][3];
    float2 r = blk_sum2(s, q, red, wid, lane);
    float mu = r.x * (1.0f / 1024.0f);
    float var = r.y * (1.0f / 1024.0f) - mu * mu;
    float inv = rsqrtf(var + 1e-5f);
    const float* gm = (const float*)&gamma[g];
    const float* bt = (const float*)&beta[g];
#pragma unroll
    for (int j = 0; j < 4; j++) {
      float n = (v[g][j] - mu) * inv * gm[j] + bt[j];
      a[g][j] = (g == 2) ? tanhf_(n) : sigmoidf_(n);
    }
  }

  float4 cp = *(const float4*)(cprev + (size_t)b * 1024 + c0);
  const float* cpe = (const float*)&cp;
  float cn[4];
#pragma unroll
  for (int j = 0; j < 4; j++)
    cn[j] = a[1][j] * cpe[j] + a[0][j] * a[2][j];

  {
    float s = cn[0] + cn[1] + cn[2] + cn[3];
    float q = cn[0]*cn[0] + cn[1]*cn[1] + cn[2]*cn[2] + cn[3]*cn[3];
    float2 r = blk_sum2(s, q, red, wid, lane);
    float mu = r.x * (1.0f / 1024.0f);
    float var = r.y * (1.0f / 1024.0f) - mu * mu;
    float inv = rsqrtf(var + 1e-5f);
    float4 gm = *(const float4*)(g_c + c0);
    float4 bt = *(const float4*)(b_c + c0);
    const float* gme = (const float*)&gm;
    const float* bte = (const float*)&bt;
    float hn[4];
#pragma unroll
    for (int j = 0; j < 4; j++) {
      float n = (cn[j] - mu) * inv * gme[j] + bte[j];
      hn[j] = a[3][j] * tanhf_(n);
    }
    *(float4*)(out + (size_t)b * 1024 + c0) = make_float4(hn[0], hn[1], hn[2], hn[3]);
    *(float4*)(out + (size_t)B_ROWS * H_DIM + (size_t)b * 1024 + c0) =
        make_float4(cn[0], cn[1], cn[2], cn[3]);
  }
}

// ---------------------------------------------------------------------------
extern "C" void kernel_launch(void* const* d_in, const int* in_sizes, int n_in,
                              void* d_out, int out_size, void* d_ws,
                              size_t ws_size, hipStream_t stream) {
  const float* x    = (const float*)d_in[0];
  const float* h    = (const float*)d_in[1];
  const float* c    = (const float*)d_in[2];
  const float* W    = (const float*)d_in[3];
  const float* bias = (const float*)d_in[4];
  const float* ln_i_g = (const float*)d_in[5];
  const float* ln_i_b = (const float*)d_in[6];
  const float* ln_f_g = (const float*)d_in[7];
  const float* ln_f_b = (const float*)d_in[8];
  const float* ln_g_g = (const float*)d_in[9];
  const float* ln_g_b = (const float*)d_in[10];
  const float* ln_o_g = (const float*)d_in[11];
  const float* ln_o_b = (const float*)d_in[12];
  const float* ln_c_g = (const float*)d_in[13];
  const float* ln_c_b = (const float*)d_in[14];

  // workspace: A_bf16 (16MB) | W_bf16 (16MB) | gates bf16 (32MB)
  unsigned short* Abf = (unsigned short*)d_ws;
  unsigned short* Wbf = Abf + (size_t)B_ROWS * K_DIM;
  unsigned short* gates = Wbf + (size_t)N_DIM * K_DIM;

  pack_a_kernel<<<(B_ROWS * K_DIM) / (4 * 256), 256, 0, stream>>>(x, h, Abf);
  pack_w_kernel<<<(N_DIM * K_DIM) / (4 * 256), 256, 0, stream>>>(W, Wbf);

  dim3 ggrid(N_DIM / 256, B_ROWS / 256);
  gemm_kernel<<<ggrid, 512, 0, stream>>>(Abf, Wbf, bias, gates);

  ln_lstm_kernel<<<B_ROWS, 256, 0, stream>>>(
      gates, c, ln_i_g, ln_i_b, ln_f_g, ln_f_b, ln_g_g, ln_g_b,
      ln_o_g, ln_o_b, ln_c_g, ln_c_b, (float*)d_out);
}

// Round 3
// 102.770 us; speedup vs baseline: 1.4531x; 1.0175x over previous
//
#include <hip/hip_runtime.h>
#include <hip/hip_bf16.h>

// Fixed shape: B=4096, I=1024, H=1024
#define B_ROWS 4096
#define H_DIM  1024
#define K_DIM  2048   // I + H
#define N_DIM  4096   // 4H
#define NT     32     // K_DIM / 64 K-tiles

typedef __attribute__((ext_vector_type(8))) short bf16x8;
typedef __attribute__((ext_vector_type(4))) float f32x4;

__device__ __forceinline__ unsigned short f2bf(float f) {
  union { float f; unsigned int u; } v; v.f = f;
  unsigned int u = v.u;
  return (unsigned short)((u + 0x7fffu + ((u >> 16) & 1u)) >> 16);
}
__device__ __forceinline__ float bf2f(unsigned short u) {
  union { unsigned int u; float f; } v; v.u = ((unsigned int)u) << 16;
  return v.f;
}

__device__ __forceinline__ void gload_lds16(const void* g, void* l) {
  __builtin_amdgcn_global_load_lds(
      (const __attribute__((address_space(1))) void*)g,
      (__attribute__((address_space(3))) void*)l, 16, 0, 0);
}

// -------- merged pack kernel: fp32 -> bf16 for A=concat(x,h) and W ---------
__global__ __launch_bounds__(256) void pack_kernel(
    const float* __restrict__ x, const float* __restrict__ h,
    const float* __restrict__ W, unsigned short* __restrict__ Abf,
    unsigned short* __restrict__ Wbf) {
  int bid = blockIdx.x;
  if (bid < 8192) {
    int t = bid * 256 + threadIdx.x;
    int e = t * 4;
    int row = e >> 11;
    int col = e & 2047;
    const float* src = (col < 1024) ? (x + (size_t)row * 1024 + col)
                                    : (h + (size_t)row * 1024 + (col - 1024));
    float4 v = *(const float4*)src;
    ushort4 o;
    o.x = f2bf(v.x); o.y = f2bf(v.y); o.z = f2bf(v.z); o.w = f2bf(v.w);
    *(ushort4*)(Abf + e) = o;
  } else {
    int t = (bid - 8192) * 256 + threadIdx.x;
    int e = t * 4;
    float4 v = *(const float4*)(W + e);
    ushort4 o;
    o.x = f2bf(v.x); o.y = f2bf(v.y); o.z = f2bf(v.z); o.w = f2bf(v.w);
    *(ushort4*)(Wbf + e) = o;
  }
}

// -------- GEMM: 256x256 tile, BK=64, 8-phase schedule, read-ahead ----------
// gates(bf16) = A(4096x2048 bf16) * W^T(4096x2048 bf16) + bias(fp32)
// 8 waves = 2(M) x 4(N); per-wave 128x64 output; LDS 128KB 2-dbuf,
// st_16x32 swizzle via pre-swizzled global source + swizzled ds_read.
// ds_reads issued ONE PHASE AHEAD so each phase's lgkmcnt(0) is a no-wait
// and the critical path is barrier + 16 MFMA + barrier.

#define STAGE(g, kt, dst) do {                              \
    gload_lds16((g) + (size_t)(kt) * 64, (dst));            \
    gload_lds16((g) + (size_t)(kt) * 64 + 32, (dst) + 1024); } while (0)

#define WAIT_LGKM0() do {                                   \
    asm volatile("s_waitcnt lgkmcnt(0)" ::: "memory");      \
    __builtin_amdgcn_sched_barrier(0); } while (0)

__global__ __launch_bounds__(512, 2) void gemm_kernel(
    const unsigned short* __restrict__ A, const unsigned short* __restrict__ W,
    const float* __restrict__ bias, unsigned short* __restrict__ C) {
  __shared__ __align__(16) char lds[131072];

  const int tid = threadIdx.x;
  const int w = tid >> 6, l = tid & 63;
  const int wm = w >> 2, wn = w & 3;            // 2 x 4 wave grid
  const int bm = blockIdx.y * 256, bn = blockIdx.x * 256;

  // swizzled ds_read lane offset within a 1KB subtile (16 rows x 32 bf16)
  const int lofs = (((l & 15) * 64) + ((l >> 4) * 16)) ^ ((l & 8) << 2);
  // inverse-swizzle lane mapping for linear global_load_lds staging
  const int lane_r = (l >> 2) & 15;
  const int lane_c = ((l & 3) * 8) ^ (((l >> 5) & 1) * 16);

  // per-wave staged row-blocks (16-row units) for each chunk
  const int rbA0 = w + (w & 4);                 // {0..3, 8..11}
  const int rbA1 = rbA0 + 4;                    // {4..7,12..15}
  const int rbB0 = ((w >> 1) << 2) + (w & 1);
  const int rbB1 = rbB0 + 2;

  const unsigned short* gA0 = A + (size_t)(bm + rbA0 * 16 + lane_r) * K_DIM + lane_c;
  const unsigned short* gA1 = A + (size_t)(bm + rbA1 * 16 + lane_r) * K_DIM + lane_c;
  const unsigned short* gB0 = W + (size_t)(bn + rbB0 * 16 + lane_r) * K_DIM + lane_c;
  const unsigned short* gB1 = W + (size_t)(bn + rbB1 * 16 + lane_r) * K_DIM + lane_c;

  char* const L0 = lds;
  char* const L1 = lds + 65536;

  f32x4 acc[8][4];
#pragma unroll
  for (int i = 0; i < 8; ++i)
#pragma unroll
    for (int j = 0; j < 4; ++j) acc[i][j] = (f32x4)0.0f;

  // ---- prologue: tile0 fully (4 chunks), tile1 first 3 chunks ----
  STAGE(gA0, 0, L0 + rbA0 * 2048);
  STAGE(gB0, 0, L0 + 32768 + rbB0 * 2048);
  STAGE(gB1, 0, L0 + 32768 + rbB1 * 2048);
  STAGE(gA1, 0, L0 + rbA1 * 2048);
  STAGE(gA0, 1, L1 + rbA0 * 2048);
  STAGE(gB0, 1, L1 + 32768 + rbB0 * 2048);
  STAGE(gB1, 1, L1 + 32768 + rbB1 * 2048);
  asm volatile("s_waitcnt vmcnt(6)" ::: "memory");   // tile0 landed
  __builtin_amdgcn_s_barrier();

  bf16x8 a0[4][2], a1[4][2], b0[2][2], b1[2][2];

  // prologue read-ahead for P1(0): a0,b0 of tile 0
#pragma unroll
  for (int mi = 0; mi < 4; ++mi)
#pragma unroll
    for (int kk = 0; kk < 2; ++kk)
      a0[mi][kk] = *(const bf16x8*)(L0 + (((wm * 8 + mi) * 2 + kk) << 10) + lofs);
#pragma unroll
  for (int ni = 0; ni < 2; ++ni)
#pragma unroll
    for (int kk = 0; kk < 2; ++kk)
      b0[ni][kk] = *(const bf16x8*)(L0 + 32768 + (((wn * 4 + ni) * 2 + kk) << 10) + lofs);

#pragma unroll 2
  for (int t = 0; t < NT; ++t) {
    const int buf = t & 1;
    char* const Lc = lds + buf * 65536;
    char* const Ln = lds + (buf ^ 1) * 65536;
    const char* const LA = Lc;
    const char* const LB = Lc + 32768;
    const char* const LAn = Ln;
    const char* const LBn = Ln + 32768;
    const int kt1 = (t + 1) & (NT - 1);   // wrapped tail prefetch: garbage, never read
    const int kt2 = (t + 2) & (NT - 1);

    // ---- P1: MFMA a0*b0 -> acc[0..3][0..1]; read b1; stage A1(t+1) ----
    STAGE(gA1, kt1, Ln + rbA1 * 2048);
    __builtin_amdgcn_s_barrier();
    WAIT_LGKM0();                          // a0,b0 (read at P4(t-1)/prologue)
    __builtin_amdgcn_s_setprio(1);
#pragma unroll
    for (int ni = 0; ni < 2; ++ni)
#pragma unroll
      for (int kk = 0; kk < 2; ++kk)
        b1[ni][kk] = *(const bf16x8*)(LB + (((wn * 4 + 2 + ni) * 2 + kk) << 10) + lofs);
#pragma unroll
    for (int mi = 0; mi < 4; ++mi)
#pragma unroll
      for (int ni = 0; ni < 2; ++ni)
#pragma unroll
        for (int kk = 0; kk < 2; ++kk)
          acc[mi][ni] = __builtin_amdgcn_mfma_f32_16x16x32_bf16(
              a0[mi][kk], b0[ni][kk], acc[mi][ni], 0, 0, 0);
    __builtin_amdgcn_s_setprio(0);
    __builtin_amdgcn_s_barrier();

    // ---- P2: MFMA a0*b1 -> acc[0..3][2..3]; read a1; stage A0(t+2) ----
    STAGE(gA0, kt2, Lc + rbA0 * 2048);
    __builtin_amdgcn_s_barrier();
    WAIT_LGKM0();                          // b1
    __builtin_amdgcn_s_setprio(1);
#pragma unroll
    for (int mi = 0; mi < 4; ++mi)
#pragma unroll
      for (int kk = 0; kk < 2; ++kk)
        a1[mi][kk] = *(const bf16x8*)(LA + (((wm * 8 + 4 + mi) * 2 + kk) << 10) + lofs);
#pragma unroll
    for (int mi = 0; mi < 4; ++mi)
#pragma unroll
      for (int ni = 0; ni < 2; ++ni)
#pragma unroll
        for (int kk = 0; kk < 2; ++kk)
          acc[mi][2 + ni] = __builtin_amdgcn_mfma_f32_16x16x32_bf16(
              a0[mi][kk], b1[ni][kk], acc[mi][2 + ni], 0, 0, 0);
    __builtin_amdgcn_s_setprio(0);
    __builtin_amdgcn_s_barrier();

    // ---- P3: MFMA a1*b1 -> acc[4..7][2..3]; stage B0(t+2) ----
    STAGE(gB0, kt2, Lc + 32768 + rbB0 * 2048);
    __builtin_amdgcn_s_barrier();
    WAIT_LGKM0();                          // a1
    __builtin_amdgcn_s_setprio(1);
#pragma unroll
    for (int mi = 0; mi < 4; ++mi)
#pragma unroll
      for (int ni = 0; ni < 2; ++ni)
#pragma unroll
        for (int kk = 0; kk < 2; ++kk)
          acc[4 + mi][2 + ni] = __builtin_amdgcn_mfma_f32_16x16x32_bf16(
              a1[mi][kk], b1[ni][kk], acc[4 + mi][2 + ni], 0, 0, 0);
    __builtin_amdgcn_s_setprio(0);
    __builtin_amdgcn_s_barrier();

    // ---- P4: MFMA a1*b0 -> acc[4..7][0..1]; stage B1(t+2); vmcnt(6);
    //      then read-ahead a0,b0 of tile t+1 from next buffer ----
    STAGE(gB1, kt2, Lc + 32768 + rbB1 * 2048);
    asm volatile("s_waitcnt vmcnt(6)" ::: "memory");   // tile t+1 landed
    __builtin_amdgcn_s_barrier();
    __builtin_amdgcn_s_setprio(1);
#pragma unroll
    for (int mi = 0; mi < 4; ++mi)
#pragma unroll
      for (int ni = 0; ni < 2; ++ni)
#pragma unroll
        for (int kk = 0; kk < 2; ++kk)
          acc[4 + mi][ni] = __builtin_amdgcn_mfma_f32_16x16x32_bf16(
              a1[mi][kk], b0[ni][kk], acc[4 + mi][ni], 0, 0, 0);
    __builtin_amdgcn_s_setprio(0);
#pragma unroll
    for (int mi = 0; mi < 4; ++mi)
#pragma unroll
      for (int kk = 0; kk < 2; ++kk)
        a0[mi][kk] = *(const bf16x8*)(LAn + (((wm * 8 + mi) * 2 + kk) << 10) + lofs);
#pragma unroll
    for (int ni = 0; ni < 2; ++ni)
#pragma unroll
      for (int kk = 0; kk < 2; ++kk)
        b0[ni][kk] = *(const bf16x8*)(LBn + (((wn * 4 + ni) * 2 + kk) << 10) + lofs);
    __builtin_amdgcn_s_barrier();
  }

  // ---- epilogue: +bias (fp32), convert to bf16, store ----
  const int lm = l & 15, lq = l >> 4;
  float bv[4];
#pragma unroll
  for (int ni = 0; ni < 4; ++ni) bv[ni] = bias[bn + wn * 64 + ni * 16 + lm];
  unsigned short* Cb = C + (size_t)(bm + wm * 128) * N_DIM + bn + wn * 64;
#pragma unroll
  for (int mi = 0; mi < 8; ++mi)
#pragma unroll
    for (int j = 0; j < 4; ++j) {
      const size_t rofs = (size_t)(mi * 16 + lq * 4 + j) * N_DIM;
#pragma unroll
      for (int ni = 0; ni < 4; ++ni)
        Cb[rofs + ni * 16 + lm] = f2bf(acc[mi][ni][j] + bv[ni]);
    }
}

// -------- fused LN + activations + cell update -----------------------------
__device__ __forceinline__ float2 blk_sum2(float s, float q, float* red,
                                           int wid, int lane) {
#pragma unroll
  for (int o = 32; o >= 1; o >>= 1) {
    s += __shfl_xor(s, o, 64);
    q += __shfl_xor(q, o, 64);
  }
  __syncthreads();
  if (lane == 0) { red[wid * 2] = s; red[wid * 2 + 1] = q; }
  __syncthreads();
  s = red[0] + red[2] + red[4] + red[6];
  q = red[1] + red[3] + red[5] + red[7];
  return make_float2(s, q);
}

__device__ __forceinline__ float sigmoidf_(float x) {
  return 1.0f / (1.0f + __expf(-x));
}
__device__ __forceinline__ float tanhf_(float x) {
  return 1.0f - 2.0f / (__expf(2.0f * x) + 1.0f);
}

__global__ __launch_bounds__(256) void ln_lstm_kernel(
    const unsigned short* __restrict__ gates, const float* __restrict__ cprev,
    const float* __restrict__ g_i, const float* __restrict__ b_i,
    const float* __restrict__ g_f, const float* __restrict__ b_f,
    const float* __restrict__ g_g, const float* __restrict__ b_g,
    const float* __restrict__ g_o, const float* __restrict__ b_o,
    const float* __restrict__ g_c, const float* __restrict__ b_c,
    float* __restrict__ out) {
  const int b = blockIdx.x;
  const int t = threadIdx.x;
  const int wid = t >> 6, lane = t & 63;
  __shared__ float red[8];

  const unsigned short* grow = gates + (size_t)b * N_DIM;
  const int c0 = t * 4;

  float v[4][4];
#pragma unroll
  for (int g = 0; g < 4; g++) {
    ushort4 raw = *(const ushort4*)(grow + g * 1024 + c0);
    v[g][0] = bf2f(raw.x); v[g][1] = bf2f(raw.y);
    v[g][2] = bf2f(raw.z); v[g][3] = bf2f(raw.w);
  }

  const float4 gamma[4] = {*(const float4*)(g_i + c0), *(const float4*)(g_f + c0),
                           *(const float4*)(g_g + c0), *(const float4*)(g_o + c0)};
  const float4 beta[4]  = {*(const float4*)(b_i + c0), *(const float4*)(b_f + c0),
                           *(const float4*)(b_g + c0), *(const float4*)(b_o + c0)};

  float a[4][4];
#pragma unroll
  for (int g = 0; g < 4; g++) {
    float s = v[g][0] + v[g][1] + v[g][2] + v[g][3];
    float q = v[g][0]*v[g][0] + v[g][1]*v[g][1] + v[g][2]*v[g][2] + v[g][3]*v[g][3];
    float2 r = blk_sum2(s, q, red, wid, lane);
    float mu = r.x * (1.0f / 1024.0f);
    float var = r.y * (1.0f / 1024.0f) - mu * mu;
    float inv = rsqrtf(var + 1e-5f);
    const float* gm = (const float*)&gamma[g];
    const float* bt = (const float*)&beta[g];
#pragma unroll
    for (int j = 0; j < 4; j++) {
      float n = (v[g][j] - mu) * inv * gm[j] + bt[j];
      a[g][j] = (g == 2) ? tanhf_(n) : sigmoidf_(n);
    }
  }

  float4 cp = *(const float4*)(cprev + (size_t)b * 1024 + c0);
  const float* cpe = (const float*)&cp;
  float cn[4];
#pragma unroll
  for (int j = 0; j < 4; j++)
    cn[j] = a[1][j] * cpe[j] + a[0][j] * a[2][j];

  {
    float s = cn[0] + cn[1] + cn[2] + cn[3];
    float q = cn[0]*cn[0] + cn[1]*cn[1] + cn[2]*cn[2] + cn[3]*cn[3];
    float2 r = blk_sum2(s, q, red, wid, lane);
    float mu = r.x * (1.0f / 1024.0f);
    float var = r.y * (1.0f / 1024.0f) - mu * mu;
    float inv = rsqrtf(var + 1e-5f);
    float4 gm = *(const float4*)(g_c + c0);
    float4 bt = *(const float4*)(b_c + c0);
    const float* gme = (const float*)&gm;
    const float* bte = (const float*)&bt;
    float hn[4];
#pragma unroll
    for (int j = 0; j < 4; j++) {
      float n = (cn[j] - mu) * inv * gme[j] + bte[j];
      hn[j] = a[3][j] * tanhf_(n);
    }
    *(float4*)(out + (size_t)b * 1024 + c0) = make_float4(hn[0], hn[1], hn[2], hn[3]);
    *(float4*)(out + (size_t)B_ROWS * H_DIM + (size_t)b * 1024 + c0) =
        make_float4(cn[0], cn[1], cn[2], cn[3]);
  }
}

// ---------------------------------------------------------------------------
extern "C" void kernel_launch(void* const* d_in, const int* in_sizes, int n_in,
                              void* d_out, int out_size, void* d_ws,
                              size_t ws_size, hipStream_t stream) {
  const float* x    = (const float*)d_in[0];
  const float* h    = (const float*)d_in[1];
  const float* c    = (const float*)d_in[2];
  const float* W    = (const float*)d_in[3];
  const float* bias = (const float*)d_in[4];
  const float* ln_i_g = (const float*)d_in[5];
  const float* ln_i_b = (const float*)d_in[6];
  const float* ln_f_g = (const float*)d_in[7];
  const float* ln_f_b = (const float*)d_in[8];
  const float* ln_g_g = (const float*)d_in[9];
  const float* ln_g_b = (const float*)d_in[10];
  const float* ln_o_g = (const float*)d_in[11];
  const float* ln_o_b = (const float*)d_in[12];
  const float* ln_c_g = (const float*)d_in[13];
  const float* ln_c_b = (const float*)d_in[14];

  // workspace: A_bf16 (16MB) | W_bf16 (16MB) | gates bf16 (32MB)
  unsigned short* Abf = (unsigned short*)d_ws;
  unsigned short* Wbf = Abf + (size_t)B_ROWS * K_DIM;
  unsigned short* gates = Wbf + (size_t)N_DIM * K_DIM;

  pack_kernel<<<16384, 256, 0, stream>>>(x, h, W, Abf, Wbf);

  dim3 ggrid(N_DIM / 256, B_ROWS / 256);
  gemm_kernel<<<ggrid, 512, 0, stream>>>(Abf, Wbf, bias, gates);

  ln_lstm_kernel<<<B_ROWS, 256, 0, stream>>>(
      gates, c, ln_i_g, ln_i_b, ln_f_g, ln_f_b, ln_g_g, ln_g_b,
      ln_o_g, ln_o_b, ln_c_g, ln_c_b, (float*)d_out);
}

// Round 4
// 102.299 us; speedup vs baseline: 1.4598x; 1.0046x over previous
//
#include <hip/hip_runtime.h>
#include <hip/hip_bf16.h>

// Fixed shape: B=4096, I=1024, H=1024
#define B_ROWS 4096
#define H_DIM  1024
#define K_DIM  2048   // I + H
#define N_DIM  4096   // 4H
#define NT     32     // K_DIM / 64 K-tiles

typedef __attribute__((ext_vector_type(8))) short bf16x8;
typedef __attribute__((ext_vector_type(4))) float f32x4;

__device__ __forceinline__ unsigned short f2bf(float f) {
  union { float f; unsigned int u; } v; v.f = f;
  unsigned int u = v.u;
  return (unsigned short)((u + 0x7fffu + ((u >> 16) & 1u)) >> 16);
}
__device__ __forceinline__ float bf2f(unsigned short u) {
  union { unsigned int u; float f; } v; v.u = ((unsigned int)u) << 16;
  return v.f;
}

__device__ __forceinline__ void gload_lds16(const void* g, void* l) {
  __builtin_amdgcn_global_load_lds(
      (const __attribute__((address_space(1))) void*)g,
      (__attribute__((address_space(3))) void*)l, 16, 0, 0);
}

// -------- merged pack kernel: fp32 -> bf16 for A=concat(x,h) and W ---------
__global__ __launch_bounds__(256) void pack_kernel(
    const float* __restrict__ x, const float* __restrict__ h,
    const float* __restrict__ W, unsigned short* __restrict__ Abf,
    unsigned short* __restrict__ Wbf) {
  int bid = blockIdx.x;
  if (bid < 8192) {
    int t = bid * 256 + threadIdx.x;
    int e = t * 4;
    int row = e >> 11;
    int col = e & 2047;
    const float* src = (col < 1024) ? (x + (size_t)row * 1024 + col)
                                    : (h + (size_t)row * 1024 + (col - 1024));
    float4 v = *(const float4*)src;
    ushort4 o;
    o.x = f2bf(v.x); o.y = f2bf(v.y); o.z = f2bf(v.z); o.w = f2bf(v.w);
    *(ushort4*)(Abf + e) = o;
  } else {
    int t = (bid - 8192) * 256 + threadIdx.x;
    int e = t * 4;
    float4 v = *(const float4*)(W + e);
    ushort4 o;
    o.x = f2bf(v.x); o.y = f2bf(v.y); o.z = f2bf(v.z); o.w = f2bf(v.w);
    *(ushort4*)(Wbf + e) = o;
  }
}

// -------- GEMM: 256x256 tile, BK=64, 4-phase/K-tile, read-ahead ------------
// gates(bf16) = A(4096x2048 bf16) * W^T(4096x2048 bf16) + bias(fp32)
// 8 waves = 2(M) x 4(N); per-wave 128x64 output; LDS 128KB 2-dbuf,
// st_16x32 swizzle via pre-swizzled global source + swizzled ds_read.
// All fragment ds_reads issued ONE PHASE AHEAD inside the MFMA cluster;
// b0 is register-double-buffered (B0R/B0W) so P4's read-ahead has no WAR
// with P4's MFMAs. XCD-aware block swizzle (4x8 rect per XCD).

#define STAGE(g, kt, dst) do {                              \
    gload_lds16((g) + (size_t)(kt) * 64, (dst));            \
    gload_lds16((g) + (size_t)(kt) * 64 + 32, (dst) + 1024); } while (0)

#define WAIT_LGKM0() do {                                   \
    asm volatile("s_waitcnt lgkmcnt(0)" ::: "memory");      \
    __builtin_amdgcn_sched_barrier(0); } while (0)

#define UNR _Pragma("unroll")

// one K-tile; BUF: LDS buffer index (compile-time), B0R: current b0 regs,
// B0W: next-tile b0 regs (written by P4's read-ahead).
#define TILE(tt, BUF, B0R, B0W)                                              \
  {                                                                          \
    char* const Lc = lds + (BUF) * 65536;                                    \
    char* const Ln = lds + ((BUF) ^ 1) * 65536;                              \
    const int kt1 = ((tt) + 1) & (NT - 1);                                   \
    const int kt2 = ((tt) + 2) & (NT - 1);                                   \
    /* ---- P1: MFMA a0*B0R -> acc[0..3][0..1]; read b1; stage A1(t+1) */    \
    STAGE(gA1, kt1, Ln + rbA1 * 2048);                                       \
    __builtin_amdgcn_s_barrier();                                            \
    WAIT_LGKM0();                                                            \
    __builtin_amdgcn_s_setprio(1);                                           \
    UNR for (int ni = 0; ni < 2; ++ni)                                       \
      UNR for (int kk = 0; kk < 2; ++kk)                                     \
        b1[ni][kk] = *(const bf16x8*)(Lc + 32768 +                           \
            (((wn * 4 + 2 + ni) * 2 + kk) << 10) + lofs);                    \
    UNR for (int mi = 0; mi < 4; ++mi)                                       \
      UNR for (int ni = 0; ni < 2; ++ni)                                     \
        UNR for (int kk = 0; kk < 2; ++kk)                                   \
          acc[mi][ni] = __builtin_amdgcn_mfma_f32_16x16x32_bf16(             \
              a0[mi][kk], B0R[ni][kk], acc[mi][ni], 0, 0, 0);                \
    __builtin_amdgcn_s_setprio(0);                                           \
    __builtin_amdgcn_s_barrier();                                            \
    /* ---- P2: MFMA a0*b1 -> acc[0..3][2..3]; read a1; stage A0(t+2) */     \
    STAGE(gA0, kt2, Lc + rbA0 * 2048);                                       \
    __builtin_amdgcn_s_barrier();                                            \
    WAIT_LGKM0();                                                            \
    __builtin_amdgcn_s_setprio(1);                                           \
    UNR for (int mi = 0; mi < 4; ++mi)                                       \
      UNR for (int kk = 0; kk < 2; ++kk)                                     \
        a1[mi][kk] = *(const bf16x8*)(Lc +                                   \
            (((wm * 8 + 4 + mi) * 2 + kk) << 10) + lofs);                    \
    UNR for (int mi = 0; mi < 4; ++mi)                                       \
      UNR for (int ni = 0; ni < 2; ++ni)                                     \
        UNR for (int kk = 0; kk < 2; ++kk)                                   \
          acc[mi][2 + ni] = __builtin_amdgcn_mfma_f32_16x16x32_bf16(         \
              a0[mi][kk], b1[ni][kk], acc[mi][2 + ni], 0, 0, 0);             \
    __builtin_amdgcn_s_setprio(0);                                           \
    __builtin_amdgcn_s_barrier();                                            \
    /* ---- P3: MFMA a1*b1 -> acc[4..7][2..3]; stage B0(t+2) */              \
    STAGE(gB0, kt2, Lc + 32768 + rbB0 * 2048);                               \
    __builtin_amdgcn_s_barrier();                                            \
    WAIT_LGKM0();                                                            \
    __builtin_amdgcn_s_setprio(1);                                           \
    UNR for (int mi = 0; mi < 4; ++mi)                                       \
      UNR for (int ni = 0; ni < 2; ++ni)                                     \
        UNR for (int kk = 0; kk < 2; ++kk)                                   \
          acc[4 + mi][2 + ni] = __builtin_amdgcn_mfma_f32_16x16x32_bf16(     \
              a1[mi][kk], b1[ni][kk], acc[4 + mi][2 + ni], 0, 0, 0);         \
    __builtin_amdgcn_s_setprio(0);                                           \
    __builtin_amdgcn_s_barrier();                                            \
    /* ---- P4: MFMA a1*B0R -> acc[4..7][0..1]; stage B1(t+2); vmcnt(6);     \
       read-ahead a0,B0W of tile t+1 (no WAR: B0W != B0R, a0 unused) */      \
    STAGE(gB1, kt2, Lc + 32768 + rbB1 * 2048);                               \
    asm volatile("s_waitcnt vmcnt(6)" ::: "memory");                         \
    __builtin_amdgcn_s_barrier();                                            \
    __builtin_amdgcn_s_setprio(1);                                           \
    UNR for (int mi = 0; mi < 4; ++mi)                                       \
      UNR for (int kk = 0; kk < 2; ++kk)                                     \
        a0[mi][kk] = *(const bf16x8*)(Ln +                                   \
            (((wm * 8 + mi) * 2 + kk) << 10) + lofs);                        \
    UNR for (int ni = 0; ni < 2; ++ni)                                       \
      UNR for (int kk = 0; kk < 2; ++kk)                                     \
        B0W[ni][kk] = *(const bf16x8*)(Ln + 32768 +                          \
            (((wn * 4 + ni) * 2 + kk) << 10) + lofs);                        \
    UNR for (int mi = 0; mi < 4; ++mi)                                       \
      UNR for (int ni = 0; ni < 2; ++ni)                                     \
        UNR for (int kk = 0; kk < 2; ++kk)                                   \
          acc[4 + mi][ni] = __builtin_amdgcn_mfma_f32_16x16x32_bf16(         \
              a1[mi][kk], B0R[ni][kk], acc[4 + mi][ni], 0, 0, 0);            \
    __builtin_amdgcn_s_setprio(0);                                           \
    __builtin_amdgcn_s_barrier();                                            \
  }

__global__ __launch_bounds__(512, 2) void gemm_kernel(
    const unsigned short* __restrict__ A, const unsigned short* __restrict__ W,
    const float* __restrict__ bias, unsigned short* __restrict__ C) {
  __shared__ __align__(16) char lds[131072];

  const int tid = threadIdx.x;
  const int w = tid >> 6, l = tid & 63;
  const int wm = w >> 2, wn = w & 3;            // 2 x 4 wave grid

  // XCD-aware swizzle: 256 blocks, 8 XCDs, each XCD owns a 4x8 rect.
  const int bid = blockIdx.x;
  const int xcd = bid & 7, li = bid >> 3;
  const int by = (xcd & 3) * 4 + (li >> 3);
  const int bx = ((xcd >> 2) << 3) + (li & 7);
  const int bm = by * 256, bn = bx * 256;

  // swizzled ds_read lane offset within a 1KB subtile (16 rows x 32 bf16)
  const int lofs = (((l & 15) * 64) + ((l >> 4) * 16)) ^ ((l & 8) << 2);
  // inverse-swizzle lane mapping for linear global_load_lds staging
  const int lane_r = (l >> 2) & 15;
  const int lane_c = ((l & 3) * 8) ^ (((l >> 5) & 1) * 16);

  // per-wave staged row-blocks (16-row units) for each chunk
  const int rbA0 = w + (w & 4);                 // {0..3, 8..11}
  const int rbA1 = rbA0 + 4;                    // {4..7,12..15}
  const int rbB0 = ((w >> 1) << 2) + (w & 1);
  const int rbB1 = rbB0 + 2;

  const unsigned short* gA0 = A + (size_t)(bm + rbA0 * 16 + lane_r) * K_DIM + lane_c;
  const unsigned short* gA1 = A + (size_t)(bm + rbA1 * 16 + lane_r) * K_DIM + lane_c;
  const unsigned short* gB0 = W + (size_t)(bn + rbB0 * 16 + lane_r) * K_DIM + lane_c;
  const unsigned short* gB1 = W + (size_t)(bn + rbB1 * 16 + lane_r) * K_DIM + lane_c;

  char* const L0 = lds;
  char* const L1 = lds + 65536;

  f32x4 acc[8][4];
#pragma unroll
  for (int i = 0; i < 8; ++i)
#pragma unroll
    for (int j = 0; j < 4; ++j) acc[i][j] = (f32x4)0.0f;

  // ---- prologue: tile0 fully (4 chunks), tile1 chunks A0,B0,B1 ----
  STAGE(gA0, 0, L0 + rbA0 * 2048);
  STAGE(gA1, 0, L0 + rbA1 * 2048);
  STAGE(gB0, 0, L0 + 32768 + rbB0 * 2048);
  STAGE(gB1, 0, L0 + 32768 + rbB1 * 2048);
  STAGE(gA0, 1, L1 + rbA0 * 2048);
  STAGE(gB0, 1, L1 + 32768 + rbB0 * 2048);
  STAGE(gB1, 1, L1 + 32768 + rbB1 * 2048);
  asm volatile("s_waitcnt vmcnt(6)" ::: "memory");   // tile0 landed
  __builtin_amdgcn_s_barrier();

  bf16x8 a0[4][2], a1[4][2], b0P[2][2], b0Q[2][2], b1[2][2];

  // prologue read-ahead for P1(0): a0, b0P of tile 0
#pragma unroll
  for (int mi = 0; mi < 4; ++mi)
#pragma unroll
    for (int kk = 0; kk < 2; ++kk)
      a0[mi][kk] = *(const bf16x8*)(L0 + (((wm * 8 + mi) * 2 + kk) << 10) + lofs);
#pragma unroll
  for (int ni = 0; ni < 2; ++ni)
#pragma unroll
    for (int kk = 0; kk < 2; ++kk)
      b0P[ni][kk] = *(const bf16x8*)(L0 + 32768 + (((wn * 4 + ni) * 2 + kk) << 10) + lofs);

  for (int t = 0; t < NT; t += 2) {
    TILE(t, 0, b0P, b0Q);
    TILE(t + 1, 1, b0Q, b0P);
  }

  // ---- epilogue: +bias (fp32), convert to bf16, store ----
  const int lm = l & 15, lq = l >> 4;
  float bv[4];
#pragma unroll
  for (int ni = 0; ni < 4; ++ni) bv[ni] = bias[bn + wn * 64 + ni * 16 + lm];
  unsigned short* Cb = C + (size_t)(bm + wm * 128) * N_DIM + bn + wn * 64;
#pragma unroll
  for (int mi = 0; mi < 8; ++mi)
#pragma unroll
    for (int j = 0; j < 4; ++j) {
      const size_t rofs = (size_t)(mi * 16 + lq * 4 + j) * N_DIM;
#pragma unroll
      for (int ni = 0; ni < 4; ++ni)
        Cb[rofs + ni * 16 + lm] = f2bf(acc[mi][ni][j] + bv[ni]);
    }
}

// -------- fused LN + activations + cell update -----------------------------
__device__ __forceinline__ float2 blk_sum2(float s, float q, float* red,
                                           int wid, int lane) {
#pragma unroll
  for (int o = 32; o >= 1; o >>= 1) {
    s += __shfl_xor(s, o, 64);
    q += __shfl_xor(q, o, 64);
  }
  __syncthreads();
  if (lane == 0) { red[wid * 2] = s; red[wid * 2 + 1] = q; }
  __syncthreads();
  s = red[0] + red[2] + red[4] + red[6];
  q = red[1] + red[3] + red[5] + red[7];
  return make_float2(s, q);
}

__device__ __forceinline__ float sigmoidf_(float x) {
  return 1.0f / (1.0f + __expf(-x));
}
__device__ __forceinline__ float tanhf_(float x) {
  return 1.0f - 2.0f / (__expf(2.0f * x) + 1.0f);
}

__global__ __launch_bounds__(256) void ln_lstm_kernel(
    const unsigned short* __restrict__ gates, const float* __restrict__ cprev,
    const float* __restrict__ g_i, const float* __restrict__ b_i,
    const float* __restrict__ g_f, const float* __restrict__ b_f,
    const float* __restrict__ g_g, const float* __restrict__ b_g,
    const float* __restrict__ g_o, const float* __restrict__ b_o,
    const float* __restrict__ g_c, const float* __restrict__ b_c,
    float* __restrict__ out) {
  const int b = blockIdx.x;
  const int t = threadIdx.x;
  const int wid = t >> 6, lane = t & 63;
  __shared__ float red[8];

  const unsigned short* grow = gates + (size_t)b * N_DIM;
  const int c0 = t * 4;

  float v[4][4];
#pragma unroll
  for (int g = 0; g < 4; g++) {
    ushort4 raw = *(const ushort4*)(grow + g * 1024 + c0);
    v[g][0] = bf2f(raw.x); v[g][1] = bf2f(raw.y);
    v[g][2] = bf2f(raw.z); v[g][3] = bf2f(raw.w);
  }

  const float4 gamma[4] = {*(const float4*)(g_i + c0), *(const float4*)(g_f + c0),
                           *(const float4*)(g_g + c0), *(const float4*)(g_o + c0)};
  const float4 beta[4]  = {*(const float4*)(b_i + c0), *(const float4*)(b_f + c0),
                           *(const float4*)(b_g + c0), *(const float4*)(b_o + c0)};

  float a[4][4];
#pragma unroll
  for (int g = 0; g < 4; g++) {
    float s = v[g][0] + v[g][1] + v[g][2] + v[g][3];
    float q = v[g][0]*v[g][0] + v[g][1]*v[g][1] + v[g][2]*v[g][2] + v[g][3]*v[g][3];
    float2 r = blk_sum2(s, q, red, wid, lane);
    float mu = r.x * (1.0f / 1024.0f);
    float var = r.y * (1.0f / 1024.0f) - mu * mu;
    float inv = rsqrtf(var + 1e-5f);
    const float* gm = (const float*)&gamma[g];
    const float* bt = (const float*)&beta[g];
#pragma unroll
    for (int j = 0; j < 4; j++) {
      float n = (v[g][j] - mu) * inv * gm[j] + bt[j];
      a[g][j] = (g == 2) ? tanhf_(n) : sigmoidf_(n);
    }
  }

  float4 cp = *(const float4*)(cprev + (size_t)b * 1024 + c0);
  const float* cpe = (const float*)&cp;
  float cn[4];
#pragma unroll
  for (int j = 0; j < 4; j++)
    cn[j] = a[1][j] * cpe[j] + a[0][j] * a[2][j];

  {
    float s = cn[0] + cn[1] + cn[2] + cn[3];
    float q = cn[0]*cn[0] + cn[1]*cn[1] + cn[2]*cn[2] + cn[3]*cn[3];
    float2 r = blk_sum2(s, q, red, wid, lane);
    float mu = r.x * (1.0f / 1024.0f);
    float var = r.y * (1.0f / 1024.0f) - mu * mu;
    float inv = rsqrtf(var + 1e-5f);
    float4 gm = *(const float4*)(g_c + c0);
    float4 bt = *(const float4*)(b_c + c0);
    const float* gme = (const float*)&gm;
    const float* bte = (const float*)&bt;
    float hn[4];
#pragma unroll
    for (int j = 0; j < 4; j++) {
      float n = (cn[j] - mu) * inv * gme[j] + bte[j];
      hn[j] = a[3][j] * tanhf_(n);
    }
    *(float4*)(out + (size_t)b * 1024 + c0) = make_float4(hn[0], hn[1], hn[2], hn[3]);
    *(float4*)(out + (size_t)B_ROWS * H_DIM + (size_t)b * 1024 + c0) =
        make_float4(cn[0], cn[1], cn[2], cn[3]);
  }
}

// ---------------------------------------------------------------------------
extern "C" void kernel_launch(void* const* d_in, const int* in_sizes, int n_in,
                              void* d_out, int out_size, void* d_ws,
                              size_t ws_size, hipStream_t stream) {
  const float* x    = (const float*)d_in[0];
  const float* h    = (const float*)d_in[1];
  const float* c    = (const float*)d_in[2];
  const float* W    = (const float*)d_in[3];
  const float* bias = (const float*)d_in[4];
  const float* ln_i_g = (const float*)d_in[5];
  const float* ln_i_b = (const float*)d_in[6];
  const float* ln_f_g = (const float*)d_in[7];
  const float* ln_f_b = (const float*)d_in[8];
  const float* ln_g_g = (const float*)d_in[9];
  const float* ln_g_b = (const float*)d_in[10];
  const float* ln_o_g = (const float*)d_in[11];
  const float* ln_o_b = (const float*)d_in[12];
  const float* ln_c_g = (const float*)d_in[13];
  const float* ln_c_b = (const float*)d_in[14];

  // workspace: A_bf16 (16MB) | W_bf16 (16MB) | gates bf16 (32MB)
  unsigned short* Abf = (unsigned short*)d_ws;
  unsigned short* Wbf = Abf + (size_t)B_ROWS * K_DIM;
  unsigned short* gates = Wbf + (size_t)N_DIM * K_DIM;

  pack_kernel<<<16384, 256, 0, stream>>>(x, h, W, Abf, Wbf);

  dim3 ggrid(256);
  gemm_kernel<<<ggrid, 512, 0, stream>>>(Abf, Wbf, bias, gates);

  ln_lstm_kernel<<<B_ROWS, 256, 0, stream>>>(
      gates, c, ln_i_g, ln_i_b, ln_f_g, ln_f_b, ln_g_g, ln_g_b,
      ln_o_g, ln_o_b, ln_c_g, ln_c_b, (float*)d_out);
}